// Round 11
// baseline (1488.452 us; speedup 1.0000x reference)
//
#include <hip/hip_runtime.h>
#include <math.h>

// ParityPonderGRU — BEST-OF assembly: r3's 4-fat-wave simple-dbuf step GEMM
// + r10's XOR-slot map (coalesced global_load_lds AND even LDS bank groups)
// + fused halt partials + MFMA gx. B=2048, E=512, H=1024, 20 steps.
// ws: gx f32[B*3H] | Whi/Wlo f16[3H*H] | hAhi hAlo hBhi hBlo f16[B*H] |
//     part_lam f32[16*B] | part_out f32[16*B] | states f32[4*B]

#define B_N 2048
#define E_N 512
#define H_N 1024
#define G3  3072
#define NSTEPS 20
#define BK 32
#define NT_H (H_N / BK)   // 32 K-steps (step GEMM)
#define NT_E (E_N / BK)   // 16 K-steps (gx GEMM)
#define NCB  (H_N / 64)   // 16 col-blocks -> halt partials

typedef __attribute__((ext_vector_type(8))) _Float16 f16x8;
typedef __attribute__((ext_vector_type(4))) _Float16 f16x4v;
typedef __attribute__((ext_vector_type(4))) float    f32x4;

#define GLDS(src, dst) \
  __builtin_amdgcn_global_load_lds( \
      (const __attribute__((address_space(1))) void*)(src), \
      (__attribute__((address_space(3))) void*)(dst), 16, 0, 0)

__device__ __forceinline__ float sigmoidf_(float x) { return 1.0f / (1.0f + expf(-x)); }

// ---------------- Fused step GEMM: gh = h @ W_hh^T (3-product split-fp16 MFMA)
// Block 128(B) x 64(H) x 3 gates; 4 waves 2x2 (wr=wv>>1 row half, wc=wv&1 col
// half); wave tile 64x32 per gate; 72 MFMA + 20 ds_read_b128 per wave per tile.
// LDS: 40 chunks of 1 KB per buffer (A-hi 0-7, A-lo 8-15, B-hi 16-27,
// B-lo 28-39), double-buffered = 80 KB.
// XOR-SLOT MAP (r10, proven correct): staging lane l of a chunk fetches global
// (row16 = l>>2, slot = (l&3)^(row16&3)^((row16>>2)&3)) — 4 lanes cover one
// row's 64 B => coalesced requests; fragment-read lane l' takes within-chunk
// 16B unit u = 4*(l'&15) + ((l'>>4)^(l'&3)^(((l'&15)>>2)&3)) — per quarter-wave
// each 4-bank group gets exactly 2 lanes (b128 floor).  Offsets loop-invariant.
// Pipeline: r3's simple dbuf — issue GLDS(t+1), compute t, __syncthreads.
__global__ __launch_bounds__(256, 1)
void gemm_step_mfma(const _Float16* __restrict__ h_hi_in,  // [B,H]
                    const _Float16* __restrict__ h_lo_in,  // [B,H]
                    const _Float16* __restrict__ Whi,      // [3H,H]
                    const _Float16* __restrict__ Wlo,      // [3H,H]
                    const float* __restrict__ b_hh,        // [3H]
                    const float* __restrict__ gx,          // [B,3H]
                    const float* __restrict__ w_lam,
                    const float* __restrict__ w_out,
                    _Float16* __restrict__ h_hi_out,
                    _Float16* __restrict__ h_lo_out,
                    float* __restrict__ part_lam,          // [NCB*B]
                    float* __restrict__ part_out)          // [NCB*B]
{
  __shared__ _Float16 lds[2][20480];                 // 81920 B
  __shared__ float pl_red[128][2], po_red[128][2];   // 2 KB

  const int tid  = threadIdx.x;
  const int lane = tid & 63;
  const int wv   = tid >> 6;     // 0..3
  const int wr   = wv >> 1;      // row half (64 rows)
  const int wc   = wv & 1;       // col half (32 cols/gate)
  const int row0 = blockIdx.y * 128;   // over B
  const int col0 = blockIdx.x * 64;    // over H
  const int cb   = blockIdx.x;         // 0..15

  const int lrow = lane & 15;
  const int q    = lane >> 4;

  // ---- staging: wave owns chunks c = wv*10 .. +9 (40 chunks of 1 KB).
  const _Float16* srcp[10];
  int ldsoff[10];
  {
    const int row16 = lane >> 2;
    const int seg_e = ((lane & 3) ^ (row16 & 3) ^ ((row16 >> 2) & 3)) * 8;
    #pragma unroll
    for (int j = 0; j < 10; ++j) {
      const int c = wv * 10 + j;
      const _Float16* s;
      if (c < 8) {                       // A-hi frag f=c: rows f*16..+15
        s = h_hi_in + (size_t)(row0 + c * 16 + row16) * H_N + seg_e;
      } else if (c < 16) {               // A-lo
        const int cc = c - 8;
        s = h_lo_in + (size_t)(row0 + cc * 16 + row16) * H_N + seg_e;
      } else if (c < 28) {               // B-hi: cc = g*4 + f (f = col-frag 0..3)
        const int cc = c - 16;
        const int wrow = (cc >> 2) * H_N + col0 + (cc & 3) * 16 + row16;
        s = Whi + (size_t)wrow * H_N + seg_e;
      } else {                           // B-lo
        const int cc = c - 28;
        const int wrow = (cc >> 2) * H_N + col0 + (cc & 3) * 16 + row16;
        s = Wlo + (size_t)wrow * H_N + seg_e;
      }
      srcp[j]   = s;
      ldsoff[j] = c * 512;               // halves
    }
  }

  // ---- loop-invariant fragment read offset (halves, within chunk)
  const int rdoff = (4 * lrow + (q ^ (lrow & 3) ^ ((lrow >> 2) & 3))) * 8;

  f32x4 acc[3][4][2];
  #pragma unroll
  for (int g = 0; g < 3; ++g)
    #pragma unroll
    for (int mi = 0; mi < 4; ++mi)
      #pragma unroll
      for (int ni = 0; ni < 2; ++ni)
        acc[g][mi][ni] = (f32x4){0.f, 0.f, 0.f, 0.f};

  auto issue = [&](int p) {
    #pragma unroll
    for (int j = 0; j < 10; ++j) { GLDS(srcp[j], &lds[p][ldsoff[j]]); srcp[j] += BK; }
  };

  issue(0);
  __syncthreads();

  for (int t = 0; t < NT_H; ++t) {
    const int p = t & 1;
    if (t + 1 < NT_H) issue(p ^ 1);      // issue early; lands by next barrier

    const _Float16* Lp = &lds[p][0];

    f16x8 ah[4], al[4];
    #pragma unroll
    for (int mi = 0; mi < 4; ++mi) {
      ah[mi] = *(const f16x8*)&Lp[(wr * 4 + mi) * 512 + rdoff];
      al[mi] = *(const f16x8*)&Lp[(8 + wr * 4 + mi) * 512 + rdoff];
    }
    f16x8 bh[3][2], bl[3][2];
    #pragma unroll
    for (int g = 0; g < 3; ++g)
      #pragma unroll
      for (int ni = 0; ni < 2; ++ni) {
        bh[g][ni] = *(const f16x8*)&Lp[(16 + g * 4 + wc * 2 + ni) * 512 + rdoff];
        bl[g][ni] = *(const f16x8*)&Lp[(28 + g * 4 + wc * 2 + ni) * 512 + rdoff];
      }

    #pragma unroll
    for (int g = 0; g < 3; ++g)
      #pragma unroll
      for (int mi = 0; mi < 4; ++mi)
        #pragma unroll
        for (int ni = 0; ni < 2; ++ni) {
          f32x4 c = acc[g][mi][ni];
          c = __builtin_amdgcn_mfma_f32_16x16x32_f16(ah[mi], bh[g][ni], c, 0, 0, 0);
          c = __builtin_amdgcn_mfma_f32_16x16x32_f16(ah[mi], bl[g][ni], c, 0, 0, 0);
          c = __builtin_amdgcn_mfma_f32_16x16x32_f16(al[mi], bh[g][ni], c, 0, 0, 0);
          acc[g][mi][ni] = c;
        }
    __syncthreads();
  }

  // Epilogue: D frag col=lane&15 (n), row=(lane>>4)*4+r (m)  [m89]
  #pragma unroll
  for (int mi = 0; mi < 4; ++mi) {
    float plr[4] = {0.f, 0.f, 0.f, 0.f};
    float por[4] = {0.f, 0.f, 0.f, 0.f};
    #pragma unroll
    for (int ni = 0; ni < 2; ++ni) {
      const int n = col0 + wc * 32 + ni * 16 + lrow;
      const float bhr = b_hh[n];
      const float bhz = b_hh[H_N + n];
      const float bhn = b_hh[2 * H_N + n];
      const float wl  = w_lam[n];
      const float wo  = w_out[n];
      #pragma unroll
      for (int r = 0; r < 4; ++r) {
        const int m = row0 + wr * 64 + mi * 16 + q * 4 + r;
        const float gr = acc[0][mi][ni][r] + bhr;
        const float gz = acc[1][mi][ni][r] + bhz;
        const float gn = acc[2][mi][ni][r] + bhn;
        const size_t gxb = (size_t)m * G3;
        const float rr = sigmoidf_(gx[gxb + n] + gr);
        const float zz = sigmoidf_(gx[gxb + H_N + n] + gz);
        const float nn = tanhf(gx[gxb + 2 * H_N + n] + rr * gn);
        const size_t hidx = (size_t)m * H_N + n;
        const float hold = (float)h_hi_in[hidx] + (float)h_lo_in[hidx];
        const float hf = (1.f - zz) * nn + zz * hold;
        const _Float16 hh = (_Float16)hf;
        h_hi_out[hidx] = hh;
        h_lo_out[hidx] = (_Float16)(hf - (float)hh);
        plr[r] += hf * wl;
        por[r] += hf * wo;
      }
    }
    #pragma unroll
    for (int r = 0; r < 4; ++r) {
      float pl = plr[r], po = por[r];
      #pragma unroll
      for (int mk = 1; mk < 16; mk <<= 1) {
        pl += __shfl_xor(pl, mk);
        po += __shfl_xor(po, mk);
      }
      if (lrow == 0) {
        pl_red[wr * 64 + mi * 16 + q * 4 + r][wc] = pl;
        po_red[wr * 64 + mi * 16 + q * 4 + r][wc] = po;
      }
    }
  }
  __syncthreads();
  if (tid < 128) {
    const int m = row0 + tid;
    part_lam[(size_t)cb * B_N + m] = pl_red[tid][0] + pl_red[tid][1];
    part_out[(size_t)cb * B_N + m] = po_red[tid][0] + po_red[tid][1];
  }
}

// ---------------- gx GEMM (MFMA): gx = x @ W_ih^T + b_ih -------------------
__global__ __launch_bounds__(256, 3)
void gemm_gx_mfma(const _Float16* __restrict__ xhi,    // [B,E]
                  const _Float16* __restrict__ xlo,
                  const _Float16* __restrict__ Wihhi,  // [3H,E]
                  const _Float16* __restrict__ Wihlo,
                  const float* __restrict__ b_ih,
                  float* __restrict__ gx)              // [B,3H]
{
  __shared__ _Float16 lds[2][12288];   // 49152 B

  const int tid  = threadIdx.x;
  const int lane = tid & 63;
  const int wv   = tid >> 6;
  const int wr   = wv >> 1;
  const int wc   = wv & 1;
  const int row0 = blockIdx.y * 128;   // over B
  const int col0 = blockIdx.x * 64;    // over 3H

  const _Float16* srcp[6];
  int ldsoff[6];
  #pragma unroll
  for (int j = 0; j < 6; ++j) {
    const int c     = wv * 6 + j;
    const int seg   = (lane & 3) * 8;
    const int row16 = lane >> 2;
    const _Float16* s;
    if (c < 8)       s = xhi   + (size_t)(row0 + c * 16 + row16) * E_N + seg;
    else if (c < 16) s = xlo   + (size_t)(row0 + (c - 8) * 16 + row16) * E_N + seg;
    else if (c < 20) s = Wihhi + (size_t)(col0 + (c - 16) * 16 + row16) * E_N + seg;
    else             s = Wihlo + (size_t)(col0 + (c - 20) * 16 + row16) * E_N + seg;
    srcp[j]   = s;
    ldsoff[j] = c * 512;
  }

  f32x4 acc[4][2];
  #pragma unroll
  for (int mi = 0; mi < 4; ++mi)
    #pragma unroll
    for (int ni = 0; ni < 2; ++ni) acc[mi][ni] = (f32x4){0.f, 0.f, 0.f, 0.f};

  const int lrow = lane & 15;
  const int lk   = (lane >> 4) * 8;
  const int q    = lane >> 4;

  #pragma unroll
  for (int j = 0; j < 6; ++j) { GLDS(srcp[j], &lds[0][ldsoff[j]]); srcp[j] += BK; }
  __syncthreads();

  for (int t = 0; t < NT_E; ++t) {
    const int p = t & 1;
    if (t + 1 < NT_E) {
      #pragma unroll
      for (int j = 0; j < 6; ++j) { GLDS(srcp[j], &lds[p ^ 1][ldsoff[j]]); srcp[j] += BK; }
    }
    f16x8 ah[4], al[4];
    #pragma unroll
    for (int mi = 0; mi < 4; ++mi) {
      const int r = wr * 64 + mi * 16 + lrow;
      ah[mi] = *(const f16x8*)&lds[p][r * 32 + lk];
      al[mi] = *(const f16x8*)&lds[p][4096 + r * 32 + lk];
    }
    f16x8 bh[2], bl[2];
    #pragma unroll
    for (int ni = 0; ni < 2; ++ni) {
      const int r = wc * 32 + ni * 16 + lrow;
      bh[ni] = *(const f16x8*)&lds[p][8192 + r * 32 + lk];
      bl[ni] = *(const f16x8*)&lds[p][10240 + r * 32 + lk];
    }
    #pragma unroll
    for (int mi = 0; mi < 4; ++mi)
      #pragma unroll
      for (int ni = 0; ni < 2; ++ni) {
        f32x4 c = acc[mi][ni];
        c = __builtin_amdgcn_mfma_f32_16x16x32_f16(ah[mi], bh[ni], c, 0, 0, 0);
        c = __builtin_amdgcn_mfma_f32_16x16x32_f16(ah[mi], bl[ni], c, 0, 0, 0);
        c = __builtin_amdgcn_mfma_f32_16x16x32_f16(al[mi], bh[ni], c, 0, 0, 0);
        acc[mi][ni] = c;
      }
    __syncthreads();
  }

  #pragma unroll
  for (int mi = 0; mi < 4; ++mi) {
    #pragma unroll
    for (int ni = 0; ni < 2; ++ni) {
      const int n = col0 + wc * 32 + ni * 16 + lrow;
      const float bi = b_ih[n];
      #pragma unroll
      for (int r = 0; r < 4; ++r) {
        const int m = row0 + wr * 64 + mi * 16 + q * 4 + r;
        gx[(size_t)m * G3 + n] = acc[mi][ni][r] + bi;
      }
    }
  }
}

// ---------------- one-time: split fp32 -> fp16 hi/lo -----------------------
__global__ __launch_bounds__(256)
void split_f32_kernel(const float* __restrict__ src,
                      _Float16* __restrict__ hi, _Float16* __restrict__ lo)
{
  const size_t base = ((size_t)blockIdx.x * 256 + threadIdx.x) * 4;
  const float4 w = *(const float4*)&src[base];
  float s[4] = {w.x, w.y, w.z, w.w};
  f16x4v h4, l4;
  #pragma unroll
  for (int e = 0; e < 4; ++e) {
    const _Float16 h = (_Float16)s[e];
    h4[e] = h;
    l4[e] = (_Float16)(s[e] - (float)h);
  }
  *(f16x4v*)&hi[base] = h4;
  *(f16x4v*)&lo[base] = l4;
}

// ---------------- h0 = gru_cell(x, 0): gh = b_hh; init states --------------
__global__ __launch_bounds__(256)
void init_h0_kernel(const float* __restrict__ gx, const float* __restrict__ b_hh,
                    _Float16* __restrict__ h_hi, _Float16* __restrict__ h_lo,
                    float* __restrict__ states)
{
    const int idx = blockIdx.x * 256 + threadIdx.x;
    const int r = idx >> 10;
    const int c = idx & (H_N - 1);
    const float rr = sigmoidf_(gx[(size_t)r * G3 + c] + b_hh[c]);
    const float zz = sigmoidf_(gx[(size_t)r * G3 + H_N + c] + b_hh[H_N + c]);
    const float nn = tanhf(gx[(size_t)r * G3 + 2 * H_N + c] + rr * b_hh[2 * H_N + c]);
    const float hf = (1.0f - zz) * nn;
    const _Float16 hh = (_Float16)hf;
    h_hi[idx] = hh;
    h_lo[idx] = (_Float16)(hf - (float)hh);
    if (idx < B_N) {
        states[idx]           = 1.0f;
        states[B_N + idx]     = 0.0f;
        states[2 * B_N + idx] = 0.0f;
        states[3 * B_N + idx] = 0.0f;
    }
}

// ---------------- halt for n=1 (reads h0 directly) --------------------------
__global__ __launch_bounds__(256)
void halt_kernel(const int n,
                 const _Float16* __restrict__ h_hi, const _Float16* __restrict__ h_lo,
                 const float* __restrict__ w_out, const float* __restrict__ b_out,
                 const float* __restrict__ w_lam, const float* __restrict__ b_lam,
                 const float* __restrict__ u,
                 float* __restrict__ states,
                 float* __restrict__ out_p, float* __restrict__ out_y,
                 float* __restrict__ out_pm, float* __restrict__ out_ym)
{
    const int row = blockIdx.x;
    const int tid = threadIdx.x;
    const size_t base = (size_t)row * H_N + (tid << 2);
    const f16x4v hh4 = *(const f16x4v*)&h_hi[base];
    const f16x4v hl4 = *(const f16x4v*)&h_lo[base];
    const float4 wl = *(const float4*)&w_lam[tid << 2];
    const float4 wo = *(const float4*)&w_out[tid << 2];
    float hv[4];
    #pragma unroll
    for (int e = 0; e < 4; ++e) hv[e] = (float)hh4[e] + (float)hl4[e];
    float s_lam = hv[0] * wl.x + hv[1] * wl.y + hv[2] * wl.z + hv[3] * wl.w;
    float s_out = hv[0] * wo.x + hv[1] * wo.y + hv[2] * wo.z + hv[3] * wo.w;
    #pragma unroll
    for (int off = 32; off > 0; off >>= 1) {
        s_lam += __shfl_down(s_lam, off);
        s_out += __shfl_down(s_out, off);
    }
    __shared__ float redl[4], redo[4];
    const int wid = tid >> 6;
    if ((tid & 63) == 0) { redl[wid] = s_lam; redo[wid] = s_out; }
    __syncthreads();
    if (tid == 0) {
        const float dlam = redl[0] + redl[1] + redl[2] + redl[3];
        const float dout = redo[0] + redo[1] + redo[2] + redo[3];
        const float lam = (n == NSTEPS) ? 1.0f : sigmoidf_(dlam + b_lam[0]);
        const float y_n = dout + b_out[0];
        float un = states[row];
        float ha = states[B_N + row];
        float pm = states[2 * B_N + row];
        float ym = states[3 * B_N + row];
        const float p_n = un * lam;
        un = un * (1.0f - lam);
        const float halt = (u[(size_t)(n - 1) * B_N + row] < lam ? 1.0f : 0.0f) * (1.0f - ha);
        pm = pm * (1.0f - halt) + p_n * halt;
        ym = ym * (1.0f - halt) + y_n * halt;
        ha += halt;
        states[row] = un;
        states[B_N + row] = ha;
        states[2 * B_N + row] = pm;
        states[3 * B_N + row] = ym;
        out_p[(size_t)(n - 1) * B_N + row] = p_n;
        out_y[(size_t)(n - 1) * B_N + row] = y_n;
        if (n == NSTEPS) { out_pm[row] = pm; out_ym[row] = ym; }
    }
}

// ---------------- halt for n>=2: sum fused partials + state update ----------
__global__ __launch_bounds__(256)
void finish_halt_kernel(const int n,
                        const float* __restrict__ part_lam,
                        const float* __restrict__ part_out,
                        const float* __restrict__ b_out, const float* __restrict__ b_lam,
                        const float* __restrict__ u,
                        float* __restrict__ states,
                        float* __restrict__ out_p, float* __restrict__ out_y,
                        float* __restrict__ out_pm, float* __restrict__ out_ym)
{
    const int row = blockIdx.x * 256 + threadIdx.x;   // 0..B-1
    float dlam = 0.f, dout = 0.f;
    #pragma unroll
    for (int cb = 0; cb < NCB; ++cb) {                // fixed order: deterministic
        dlam += part_lam[(size_t)cb * B_N + row];
        dout += part_out[(size_t)cb * B_N + row];
    }
    const float lam = (n == NSTEPS) ? 1.0f : sigmoidf_(dlam + b_lam[0]);
    const float y_n = dout + b_out[0];
    float un = states[row];
    float ha = states[B_N + row];
    float pm = states[2 * B_N + row];
    float ym = states[3 * B_N + row];
    const float p_n = un * lam;
    un = un * (1.0f - lam);
    const float halt = (u[(size_t)(n - 1) * B_N + row] < lam ? 1.0f : 0.0f) * (1.0f - ha);
    pm = pm * (1.0f - halt) + p_n * halt;
    ym = ym * (1.0f - halt) + y_n * halt;
    ha += halt;
    states[row] = un;
    states[B_N + row] = ha;
    states[2 * B_N + row] = pm;
    states[3 * B_N + row] = ym;
    out_p[(size_t)(n - 1) * B_N + row] = p_n;
    out_y[(size_t)(n - 1) * B_N + row] = y_n;
    if (n == NSTEPS) { out_pm[row] = pm; out_ym[row] = ym; }
}

extern "C" void kernel_launch(void* const* d_in, const int* in_sizes, int n_in,
                              void* d_out, int out_size, void* d_ws, size_t ws_size,
                              hipStream_t stream) {
    const float* x     = (const float*)d_in[0];
    const float* W_ih  = (const float*)d_in[1];
    const float* W_hh  = (const float*)d_in[2];
    const float* b_ih  = (const float*)d_in[3];
    const float* b_hh  = (const float*)d_in[4];
    const float* w_out = (const float*)d_in[5];
    const float* b_out = (const float*)d_in[6];
    const float* w_lam = (const float*)d_in[7];
    const float* b_lam = (const float*)d_in[8];
    const float* u     = (const float*)d_in[9];

    float* out_p  = (float*)d_out;
    float* out_y  = out_p + (size_t)NSTEPS * B_N;
    float* out_pm = out_y + (size_t)NSTEPS * B_N;
    float* out_ym = out_pm + B_N;

    float* ws = (float*)d_ws;
    float*     gx   = ws;                                    // B*3H f32
    _Float16*  Whi  = (_Float16*)(gx + (size_t)B_N * G3);    // 3H*H f16
    _Float16*  Wlo  = Whi + (size_t)G3 * H_N;
    _Float16*  hAhi = Wlo + (size_t)G3 * H_N;                // B*H f16
    _Float16*  hAlo = hAhi + (size_t)B_N * H_N;
    _Float16*  hBhi = hAlo + (size_t)B_N * H_N;
    _Float16*  hBlo = hBhi + (size_t)B_N * H_N;
    float*     part_lam = (float*)(hBlo + (size_t)B_N * H_N); // NCB*B f32
    float*     part_out = part_lam + (size_t)NCB * B_N;
    float*     states   = part_out + (size_t)NCB * B_N;       // 4*B f32

    const dim3 blk(256);
    split_f32_kernel<<<dim3((size_t)G3 * H_N / 1024), blk, 0, stream>>>(W_hh, Whi, Wlo);
    split_f32_kernel<<<dim3((size_t)G3 * E_N / 1024), blk, 0, stream>>>(W_ih, hAhi, hAlo);
    split_f32_kernel<<<dim3((size_t)B_N * E_N / 1024), blk, 0, stream>>>(x, hBhi, hBlo);
    gemm_gx_mfma<<<dim3(G3 / 64, B_N / 128), blk, 0, stream>>>(hBhi, hBlo, hAhi, hAlo, b_ih, gx);
    init_h0_kernel<<<dim3(B_N * H_N / 256), blk, 0, stream>>>(gx, b_hh, hAhi, hAlo, states);

    _Float16 *hchi = hAhi, *hclo = hAlo, *hnhi = hBhi, *hnlo = hBlo;
    for (int n = 1; n <= NSTEPS; ++n) {
        if (n == 1) {
            halt_kernel<<<dim3(B_N), blk, 0, stream>>>(n, hchi, hclo, w_out, b_out,
                                                       w_lam, b_lam, u, states,
                                                       out_p, out_y, out_pm, out_ym);
        } else {
            finish_halt_kernel<<<dim3(B_N / 256), blk, 0, stream>>>(n, part_lam, part_out,
                                                                    b_out, b_lam, u, states,
                                                                    out_p, out_y, out_pm, out_ym);
        }
        if (n < NSTEPS) {
            gemm_step_mfma<<<dim3(H_N / 64, B_N / 128), blk, 0, stream>>>(
                hchi, hclo, Whi, Wlo, b_hh, gx, w_lam, w_out, hnhi, hnlo, part_lam, part_out);
            _Float16* t;
            t = hchi; hchi = hnhi; hnhi = t;
            t = hclo; hclo = hnlo; hnlo = t;
        }
    }
}

// Round 12
// 1360.322 us; speedup vs baseline: 1.0942x; 1.0942x over previous
//
#include <hip/hip_runtime.h>
#include <math.h>

// ParityPonderGRU — r3-verbatim step loop (proven fastest: lane-linear LDS,
// coalesced staging, 4 fat waves, simple dbuf) + MFMA gx + halt fused into
// the step kernel (prologue finish_halt, epilogue partial dots, parity-
// double-buffered partials). B=2048, E=512, H=1024, 20 steps.
// ws: gx f32[B*3H] | Whi/Wlo f16[3H*H] | hAhi hAlo hBhi hBlo f16[B*H] |
//     part[2][2][16*B] f32 | states f32[4*B]

#define B_N 2048
#define E_N 512
#define H_N 1024
#define G3  3072
#define NSTEPS 20
#define BK 32
#define NT_H (H_N / BK)   // 32 K-steps (step GEMM)
#define NT_E (E_N / BK)   // 16 K-steps (gx GEMM)
#define NCB  (H_N / 64)   // 16 col-blocks -> halt partials

typedef __attribute__((ext_vector_type(8))) _Float16 f16x8;
typedef __attribute__((ext_vector_type(4))) _Float16 f16x4v;
typedef __attribute__((ext_vector_type(4))) float    f32x4;

#define GLDS(src, dst) \
  __builtin_amdgcn_global_load_lds( \
      (const __attribute__((address_space(1))) void*)(src), \
      (__attribute__((address_space(3))) void*)(dst), 16, 0, 0)

__device__ __forceinline__ float sigmoidf_(float x) { return 1.0f / (1.0f + expf(-x)); }

// ---------------- Fused step GEMM: gh = h @ W_hh^T (3-product split-fp16 MFMA)
// r3-verbatim loop: block 128(B) x 64(H) x 3 gates; 4 waves 2x2; wave tile
// 64x32/gate. LDS [row][32]-half rows, chunks of 16 rows (1 KB) staged
// lane-linear (4 lanes cover one row's 64 B -> coalesced). Sections per
// 40-KB buffer (halves): Ahi[0,4096) Alo[4096,8192) Bhi[8192,14336)
// Blo[14336,20480); double-buffered (80 KB). Simple dbuf: issue GLDS(t+1),
// compute t, __syncthreads. (8-way frag-read bank aliasing accepted: fixing
// it regressed in r9/r11 — latency-bound, not conflict-bound.)
// NEW: prologue performs finish_halt(n) on cb==0 blocks (overlapped with
// tile-0 load flight); epilogue reduces h.w_lam / h.w_out partials.
__global__ __launch_bounds__(256, 1)
void gemm_step_mfma(const int n, const int do_halt,
                    const _Float16* __restrict__ h_hi_in,  // [B,H]
                    const _Float16* __restrict__ h_lo_in,  // [B,H]
                    const _Float16* __restrict__ Whi,      // [3H,H]
                    const _Float16* __restrict__ Wlo,      // [3H,H]
                    const float* __restrict__ b_hh,        // [3H]
                    const float* __restrict__ gx,          // [B,3H]
                    const float* __restrict__ w_lam,
                    const float* __restrict__ w_out,
                    const float* __restrict__ b_out, const float* __restrict__ b_lam,
                    const float* __restrict__ u,
                    _Float16* __restrict__ h_hi_out,
                    _Float16* __restrict__ h_lo_out,
                    const float* __restrict__ part_lam_in,   // [NCB*B] (parity n-1)
                    const float* __restrict__ part_out_in,
                    float* __restrict__ part_lam_out,        // [NCB*B] (parity n)
                    float* __restrict__ part_out_out,
                    float* __restrict__ states,
                    float* __restrict__ out_p, float* __restrict__ out_y)
{
  __shared__ _Float16 lds[2][20480];                 // 81920 B
  __shared__ float pl_red[128][2], po_red[128][2];   // 2 KB

  const int tid  = threadIdx.x;
  const int lane = tid & 63;
  const int wv   = tid >> 6;     // 0..3
  const int wr   = wv >> 1;      // row half (64 rows)
  const int wc   = wv & 1;       // col half (32 cols/gate)
  const int row0 = blockIdx.y * 128;   // over B
  const int col0 = blockIdx.x * 64;    // over H
  const int cb   = blockIdx.x;         // 0..15

  // staging (r3-verbatim): 40 chunks of 1 KB = 16 rows x 32 halves,
  // lane-linear: lane -> (row16 = lane>>2, seg = (lane&3)*8). Wave owns 10.
  const _Float16* srcp[10];
  int ldsoff[10];
  #pragma unroll
  for (int j = 0; j < 10; ++j) {
    const int c     = wv * 10 + j;
    const int seg   = (lane & 3) * 8;
    const int row16 = lane >> 2;
    const _Float16* s;
    if (c < 8) {
      s = h_hi_in + (size_t)(row0 + c * 16 + row16) * H_N + seg;
    } else if (c < 16) {
      s = h_lo_in + (size_t)(row0 + (c - 8) * 16 + row16) * H_N + seg;
    } else if (c < 28) {
      const int br = (c - 16) * 16 + row16;               // 0..191
      s = Whi + (size_t)((br >> 6) * H_N + col0 + (br & 63)) * H_N + seg;
    } else {
      const int br = (c - 28) * 16 + row16;
      s = Wlo + (size_t)((br >> 6) * H_N + col0 + (br & 63)) * H_N + seg;
    }
    srcp[j]   = s;
    ldsoff[j] = c * 512;
  }

  f32x4 acc[3][4][2];
  #pragma unroll
  for (int g = 0; g < 3; ++g)
    #pragma unroll
    for (int mi = 0; mi < 4; ++mi)
      #pragma unroll
      for (int ni = 0; ni < 2; ++ni)
        acc[g][mi][ni] = (f32x4){0.f, 0.f, 0.f, 0.f};

  const int lrow = lane & 15;
  const int lk   = (lane >> 4) * 8;
  const int q    = lane >> 4;

  auto issue = [&](int p) {
    #pragma unroll
    for (int j = 0; j < 10; ++j) { GLDS(srcp[j], &lds[p][ldsoff[j]]); srcp[j] += BK; }
  };

  // stage tile 0, then do the fused finish_halt while loads are in flight
  issue(0);
  if (do_halt && cb == 0 && tid < 128) {
    const int row = row0 + tid;
    float dlam = 0.f, dout = 0.f;
    #pragma unroll
    for (int cq = 0; cq < NCB; ++cq) {           // fixed order: deterministic
      dlam += part_lam_in[(size_t)cq * B_N + row];
      dout += part_out_in[(size_t)cq * B_N + row];
    }
    const float lam = sigmoidf_(dlam + b_lam[0]);   // n <= 19 here, no force
    const float y_n = dout + b_out[0];
    float un = states[row];
    float ha = states[B_N + row];
    float pm = states[2 * B_N + row];
    float ym = states[3 * B_N + row];
    const float p_n = un * lam;
    un = un * (1.0f - lam);
    const float halt = (u[(size_t)(n - 1) * B_N + row] < lam ? 1.0f : 0.0f) * (1.0f - ha);
    pm = pm * (1.0f - halt) + p_n * halt;
    ym = ym * (1.0f - halt) + y_n * halt;
    ha += halt;
    states[row] = un;
    states[B_N + row] = ha;
    states[2 * B_N + row] = pm;
    states[3 * B_N + row] = ym;
    out_p[(size_t)(n - 1) * B_N + row] = p_n;
    out_y[(size_t)(n - 1) * B_N + row] = y_n;
  }
  __syncthreads();

  for (int t = 0; t < NT_H; ++t) {
    const int p = t & 1;
    if (t + 1 < NT_H) issue(p ^ 1);       // issue early; lands by next barrier

    f16x8 ah[4], al[4];
    #pragma unroll
    for (int mi = 0; mi < 4; ++mi) {
      const int r = wr * 64 + mi * 16 + lrow;
      ah[mi] = *(const f16x8*)&lds[p][r * 32 + lk];
      al[mi] = *(const f16x8*)&lds[p][4096 + r * 32 + lk];
    }
    f16x8 bh[3][2], bl[3][2];
    #pragma unroll
    for (int g = 0; g < 3; ++g)
      #pragma unroll
      for (int ni = 0; ni < 2; ++ni) {
        const int r = g * 64 + wc * 32 + ni * 16 + lrow;
        bh[g][ni] = *(const f16x8*)&lds[p][8192 + r * 32 + lk];
        bl[g][ni] = *(const f16x8*)&lds[p][14336 + r * 32 + lk];
      }
    #pragma unroll
    for (int g = 0; g < 3; ++g)
      #pragma unroll
      for (int mi = 0; mi < 4; ++mi)
        #pragma unroll
        for (int ni = 0; ni < 2; ++ni) {
          f32x4 c = acc[g][mi][ni];
          c = __builtin_amdgcn_mfma_f32_16x16x32_f16(ah[mi], bh[g][ni], c, 0, 0, 0);
          c = __builtin_amdgcn_mfma_f32_16x16x32_f16(ah[mi], bl[g][ni], c, 0, 0, 0);
          c = __builtin_amdgcn_mfma_f32_16x16x32_f16(al[mi], bh[g][ni], c, 0, 0, 0);
          acc[g][mi][ni] = c;
        }
    __syncthreads();
  }

  // Epilogue (r3-verbatim + partial dots): D frag col=lane&15, row=(lane>>4)*4+r
  #pragma unroll
  for (int mi = 0; mi < 4; ++mi) {
    float plr[4] = {0.f, 0.f, 0.f, 0.f};
    float por[4] = {0.f, 0.f, 0.f, 0.f};
    #pragma unroll
    for (int ni = 0; ni < 2; ++ni) {
      const int nn_ = col0 + wc * 32 + ni * 16 + lrow;
      const float bhr = b_hh[nn_];
      const float bhz = b_hh[H_N + nn_];
      const float bhn = b_hh[2 * H_N + nn_];
      const float wl  = w_lam[nn_];
      const float wo  = w_out[nn_];
      #pragma unroll
      for (int r = 0; r < 4; ++r) {
        const int m = row0 + wr * 64 + mi * 16 + q * 4 + r;
        const float gr = acc[0][mi][ni][r] + bhr;
        const float gz = acc[1][mi][ni][r] + bhz;
        const float gn = acc[2][mi][ni][r] + bhn;
        const size_t gxb = (size_t)m * G3;
        const float rr = sigmoidf_(gx[gxb + nn_] + gr);
        const float zz = sigmoidf_(gx[gxb + H_N + nn_] + gz);
        const float nn = tanhf(gx[gxb + 2 * H_N + nn_] + rr * gn);
        const size_t hidx = (size_t)m * H_N + nn_;
        const float hold = (float)h_hi_in[hidx] + (float)h_lo_in[hidx];
        const float hf = (1.f - zz) * nn + zz * hold;
        const _Float16 hh = (_Float16)hf;
        h_hi_out[hidx] = hh;
        h_lo_out[hidx] = (_Float16)(hf - (float)hh);
        plr[r] += hf * wl;
        por[r] += hf * wo;
      }
    }
    #pragma unroll
    for (int r = 0; r < 4; ++r) {
      float pl = plr[r], po = por[r];
      #pragma unroll
      for (int mk = 1; mk < 16; mk <<= 1) {
        pl += __shfl_xor(pl, mk);
        po += __shfl_xor(po, mk);
      }
      if (lrow == 0) {
        pl_red[wr * 64 + mi * 16 + q * 4 + r][wc] = pl;
        po_red[wr * 64 + mi * 16 + q * 4 + r][wc] = po;
      }
    }
  }
  __syncthreads();
  if (tid < 128) {
    const int m = row0 + tid;
    part_lam_out[(size_t)cb * B_N + m] = pl_red[tid][0] + pl_red[tid][1];
    part_out_out[(size_t)cb * B_N + m] = po_red[tid][0] + po_red[tid][1];
  }
}

// ---------------- gx GEMM (MFMA): gx = x @ W_ih^T + b_ih -------------------
__global__ __launch_bounds__(256, 3)
void gemm_gx_mfma(const _Float16* __restrict__ xhi,    // [B,E]
                  const _Float16* __restrict__ xlo,
                  const _Float16* __restrict__ Wihhi,  // [3H,E]
                  const _Float16* __restrict__ Wihlo,
                  const float* __restrict__ b_ih,
                  float* __restrict__ gx)              // [B,3H]
{
  __shared__ _Float16 lds[2][12288];   // 49152 B

  const int tid  = threadIdx.x;
  const int lane = tid & 63;
  const int wv   = tid >> 6;
  const int wr   = wv >> 1;
  const int wc   = wv & 1;
  const int row0 = blockIdx.y * 128;   // over B
  const int col0 = blockIdx.x * 64;    // over 3H

  const _Float16* srcp[6];
  int ldsoff[6];
  #pragma unroll
  for (int j = 0; j < 6; ++j) {
    const int c     = wv * 6 + j;
    const int seg   = (lane & 3) * 8;
    const int row16 = lane >> 2;
    const _Float16* s;
    if (c < 8)       s = xhi   + (size_t)(row0 + c * 16 + row16) * E_N + seg;
    else if (c < 16) s = xlo   + (size_t)(row0 + (c - 8) * 16 + row16) * E_N + seg;
    else if (c < 20) s = Wihhi + (size_t)(col0 + (c - 16) * 16 + row16) * E_N + seg;
    else             s = Wihlo + (size_t)(col0 + (c - 20) * 16 + row16) * E_N + seg;
    srcp[j]   = s;
    ldsoff[j] = c * 512;
  }

  f32x4 acc[4][2];
  #pragma unroll
  for (int mi = 0; mi < 4; ++mi)
    #pragma unroll
    for (int ni = 0; ni < 2; ++ni) acc[mi][ni] = (f32x4){0.f, 0.f, 0.f, 0.f};

  const int lrow = lane & 15;
  const int lk   = (lane >> 4) * 8;
  const int q    = lane >> 4;

  #pragma unroll
  for (int j = 0; j < 6; ++j) { GLDS(srcp[j], &lds[0][ldsoff[j]]); srcp[j] += BK; }
  __syncthreads();

  for (int t = 0; t < NT_E; ++t) {
    const int p = t & 1;
    if (t + 1 < NT_E) {
      #pragma unroll
      for (int j = 0; j < 6; ++j) { GLDS(srcp[j], &lds[p ^ 1][ldsoff[j]]); srcp[j] += BK; }
    }
    f16x8 ah[4], al[4];
    #pragma unroll
    for (int mi = 0; mi < 4; ++mi) {
      const int r = wr * 64 + mi * 16 + lrow;
      ah[mi] = *(const f16x8*)&lds[p][r * 32 + lk];
      al[mi] = *(const f16x8*)&lds[p][4096 + r * 32 + lk];
    }
    f16x8 bh[2], bl[2];
    #pragma unroll
    for (int ni = 0; ni < 2; ++ni) {
      const int r = wc * 32 + ni * 16 + lrow;
      bh[ni] = *(const f16x8*)&lds[p][8192 + r * 32 + lk];
      bl[ni] = *(const f16x8*)&lds[p][10240 + r * 32 + lk];
    }
    #pragma unroll
    for (int mi = 0; mi < 4; ++mi)
      #pragma unroll
      for (int ni = 0; ni < 2; ++ni) {
        f32x4 c = acc[mi][ni];
        c = __builtin_amdgcn_mfma_f32_16x16x32_f16(ah[mi], bh[ni], c, 0, 0, 0);
        c = __builtin_amdgcn_mfma_f32_16x16x32_f16(ah[mi], bl[ni], c, 0, 0, 0);
        c = __builtin_amdgcn_mfma_f32_16x16x32_f16(al[mi], bh[ni], c, 0, 0, 0);
        acc[mi][ni] = c;
      }
    __syncthreads();
  }

  #pragma unroll
  for (int mi = 0; mi < 4; ++mi) {
    #pragma unroll
    for (int ni = 0; ni < 2; ++ni) {
      const int n = col0 + wc * 32 + ni * 16 + lrow;
      const float bi = b_ih[n];
      #pragma unroll
      for (int r = 0; r < 4; ++r) {
        const int m = row0 + wr * 64 + mi * 16 + q * 4 + r;
        gx[(size_t)m * G3 + n] = acc[mi][ni][r] + bi;
      }
    }
  }
}

// ---------------- one-time: split fp32 -> fp16 hi/lo -----------------------
__global__ __launch_bounds__(256)
void split_f32_kernel(const float* __restrict__ src,
                      _Float16* __restrict__ hi, _Float16* __restrict__ lo)
{
  const size_t base = ((size_t)blockIdx.x * 256 + threadIdx.x) * 4;
  const float4 w = *(const float4*)&src[base];
  float s[4] = {w.x, w.y, w.z, w.w};
  f16x4v h4, l4;
  #pragma unroll
  for (int e = 0; e < 4; ++e) {
    const _Float16 h = (_Float16)s[e];
    h4[e] = h;
    l4[e] = (_Float16)(s[e] - (float)h);
  }
  *(f16x4v*)&hi[base] = h4;
  *(f16x4v*)&lo[base] = l4;
}

// ---------------- h0 = gru_cell(x, 0): gh = b_hh; init states --------------
__global__ __launch_bounds__(256)
void init_h0_kernel(const float* __restrict__ gx, const float* __restrict__ b_hh,
                    _Float16* __restrict__ h_hi, _Float16* __restrict__ h_lo,
                    float* __restrict__ states)
{
    const int idx = blockIdx.x * 256 + threadIdx.x;
    const int r = idx >> 10;
    const int c = idx & (H_N - 1);
    const float rr = sigmoidf_(gx[(size_t)r * G3 + c] + b_hh[c]);
    const float zz = sigmoidf_(gx[(size_t)r * G3 + H_N + c] + b_hh[H_N + c]);
    const float nn = tanhf(gx[(size_t)r * G3 + 2 * H_N + c] + rr * b_hh[2 * H_N + c]);
    const float hf = (1.0f - zz) * nn;
    const _Float16 hh = (_Float16)hf;
    h_hi[idx] = hh;
    h_lo[idx] = (_Float16)(hf - (float)hh);
    if (idx < B_N) {
        states[idx]           = 1.0f;
        states[B_N + idx]     = 0.0f;
        states[2 * B_N + idx] = 0.0f;
        states[3 * B_N + idx] = 0.0f;
    }
}

// ---------------- halt for n=1 (reads h0 directly) --------------------------
__global__ __launch_bounds__(256)
void halt_kernel(const int n,
                 const _Float16* __restrict__ h_hi, const _Float16* __restrict__ h_lo,
                 const float* __restrict__ w_out, const float* __restrict__ b_out,
                 const float* __restrict__ w_lam, const float* __restrict__ b_lam,
                 const float* __restrict__ u,
                 float* __restrict__ states,
                 float* __restrict__ out_p, float* __restrict__ out_y,
                 float* __restrict__ out_pm, float* __restrict__ out_ym)
{
    const int row = blockIdx.x;
    const int tid = threadIdx.x;
    const size_t base = (size_t)row * H_N + (tid << 2);
    const f16x4v hh4 = *(const f16x4v*)&h_hi[base];
    const f16x4v hl4 = *(const f16x4v*)&h_lo[base];
    const float4 wl = *(const float4*)&w_lam[tid << 2];
    const float4 wo = *(const float4*)&w_out[tid << 2];
    float hv[4];
    #pragma unroll
    for (int e = 0; e < 4; ++e) hv[e] = (float)hh4[e] + (float)hl4[e];
    float s_lam = hv[0] * wl.x + hv[1] * wl.y + hv[2] * wl.z + hv[3] * wl.w;
    float s_out = hv[0] * wo.x + hv[1] * wo.y + hv[2] * wo.z + hv[3] * wo.w;
    #pragma unroll
    for (int off = 32; off > 0; off >>= 1) {
        s_lam += __shfl_down(s_lam, off);
        s_out += __shfl_down(s_out, off);
    }
    __shared__ float redl[4], redo[4];
    const int wid = tid >> 6;
    if ((tid & 63) == 0) { redl[wid] = s_lam; redo[wid] = s_out; }
    __syncthreads();
    if (tid == 0) {
        const float dlam = redl[0] + redl[1] + redl[2] + redl[3];
        const float dout = redo[0] + redo[1] + redo[2] + redo[3];
        const float lam = (n == NSTEPS) ? 1.0f : sigmoidf_(dlam + b_lam[0]);
        const float y_n = dout + b_out[0];
        float un = states[row];
        float ha = states[B_N + row];
        float pm = states[2 * B_N + row];
        float ym = states[3 * B_N + row];
        const float p_n = un * lam;
        un = un * (1.0f - lam);
        const float halt = (u[(size_t)(n - 1) * B_N + row] < lam ? 1.0f : 0.0f) * (1.0f - ha);
        pm = pm * (1.0f - halt) + p_n * halt;
        ym = ym * (1.0f - halt) + y_n * halt;
        ha += halt;
        states[row] = un;
        states[B_N + row] = ha;
        states[2 * B_N + row] = pm;
        states[3 * B_N + row] = ym;
        out_p[(size_t)(n - 1) * B_N + row] = p_n;
        out_y[(size_t)(n - 1) * B_N + row] = y_n;
        if (n == NSTEPS) { out_pm[row] = pm; out_ym[row] = ym; }
    }
}

// ---------------- halt for n=20: sum partials + final outputs ---------------
__global__ __launch_bounds__(256)
void finish_halt_kernel(const int n,
                        const float* __restrict__ part_lam,
                        const float* __restrict__ part_out,
                        const float* __restrict__ b_out, const float* __restrict__ b_lam,
                        const float* __restrict__ u,
                        float* __restrict__ states,
                        float* __restrict__ out_p, float* __restrict__ out_y,
                        float* __restrict__ out_pm, float* __restrict__ out_ym)
{
    const int row = blockIdx.x * 256 + threadIdx.x;   // 0..B-1
    float dlam = 0.f, dout = 0.f;
    #pragma unroll
    for (int cb = 0; cb < NCB; ++cb) {                // fixed order: deterministic
        dlam += part_lam[(size_t)cb * B_N + row];
        dout += part_out[(size_t)cb * B_N + row];
    }
    const float lam = (n == NSTEPS) ? 1.0f : sigmoidf_(dlam + b_lam[0]);
    const float y_n = dout + b_out[0];
    float un = states[row];
    float ha = states[B_N + row];
    float pm = states[2 * B_N + row];
    float ym = states[3 * B_N + row];
    const float p_n = un * lam;
    un = un * (1.0f - lam);
    const float halt = (u[(size_t)(n - 1) * B_N + row] < lam ? 1.0f : 0.0f) * (1.0f - ha);
    pm = pm * (1.0f - halt) + p_n * halt;
    ym = ym * (1.0f - halt) + y_n * halt;
    ha += halt;
    states[row] = un;
    states[B_N + row] = ha;
    states[2 * B_N + row] = pm;
    states[3 * B_N + row] = ym;
    out_p[(size_t)(n - 1) * B_N + row] = p_n;
    out_y[(size_t)(n - 1) * B_N + row] = y_n;
    if (n == NSTEPS) { out_pm[row] = pm; out_ym[row] = ym; }
}

extern "C" void kernel_launch(void* const* d_in, const int* in_sizes, int n_in,
                              void* d_out, int out_size, void* d_ws, size_t ws_size,
                              hipStream_t stream) {
    const float* x     = (const float*)d_in[0];
    const float* W_ih  = (const float*)d_in[1];
    const float* W_hh  = (const float*)d_in[2];
    const float* b_ih  = (const float*)d_in[3];
    const float* b_hh  = (const float*)d_in[4];
    const float* w_out = (const float*)d_in[5];
    const float* b_out = (const float*)d_in[6];
    const float* w_lam = (const float*)d_in[7];
    const float* b_lam = (const float*)d_in[8];
    const float* u     = (const float*)d_in[9];

    float* out_p  = (float*)d_out;
    float* out_y  = out_p + (size_t)NSTEPS * B_N;
    float* out_pm = out_y + (size_t)NSTEPS * B_N;
    float* out_ym = out_pm + B_N;

    float* ws = (float*)d_ws;
    float*     gx   = ws;                                    // B*3H f32
    _Float16*  Whi  = (_Float16*)(gx + (size_t)B_N * G3);    // 3H*H f16
    _Float16*  Wlo  = Whi + (size_t)G3 * H_N;
    _Float16*  hAhi = Wlo + (size_t)G3 * H_N;                // B*H f16
    _Float16*  hAlo = hAhi + (size_t)B_N * H_N;
    _Float16*  hBhi = hAlo + (size_t)B_N * H_N;
    _Float16*  hBlo = hBhi + (size_t)B_N * H_N;
    float*     pl0  = (float*)(hBlo + (size_t)B_N * H_N);    // parity-0 partials
    float*     po0  = pl0 + (size_t)NCB * B_N;
    float*     pl1  = po0 + (size_t)NCB * B_N;               // parity-1 partials
    float*     po1  = pl1 + (size_t)NCB * B_N;
    float*     states = po1 + (size_t)NCB * B_N;             // 4*B f32

    const dim3 blk(256);
    split_f32_kernel<<<dim3((size_t)G3 * H_N / 1024), blk, 0, stream>>>(W_hh, Whi, Wlo);
    split_f32_kernel<<<dim3((size_t)G3 * E_N / 1024), blk, 0, stream>>>(W_ih, hAhi, hAlo);
    split_f32_kernel<<<dim3((size_t)B_N * E_N / 1024), blk, 0, stream>>>(x, hBhi, hBlo);
    gemm_gx_mfma<<<dim3(G3 / 64, B_N / 128), blk, 0, stream>>>(hBhi, hBlo, hAhi, hAlo, b_ih, gx);
    init_h0_kernel<<<dim3(B_N * H_N / 256), blk, 0, stream>>>(gx, b_hh, hAhi, hAlo, states);

    // halt(1) on h0 (standalone: needs full-row dots of h0)
    halt_kernel<<<dim3(B_N), blk, 0, stream>>>(1, hAhi, hAlo, w_out, b_out,
                                               w_lam, b_lam, u, states,
                                               out_p, out_y, out_pm, out_ym);

    _Float16 *hchi = hAhi, *hclo = hAlo, *hnhi = hBhi, *hnlo = hBlo;
    for (int n = 1; n <= NSTEPS - 1; ++n) {
        // epilogue writes parity n&1; prologue (n>=2) reads parity (n-1)&1
        float* pli = ((n - 1) & 1) ? pl1 : pl0;
        float* poi = ((n - 1) & 1) ? po1 : po0;
        float* plo = (n & 1) ? pl1 : pl0;
        float* poo = (n & 1) ? po1 : po0;
        gemm_step_mfma<<<dim3(H_N / 64, B_N / 128), blk, 0, stream>>>(
            n, (n >= 2) ? 1 : 0,
            hchi, hclo, Whi, Wlo, b_hh, gx, w_lam, w_out, b_out, b_lam, u,
            hnhi, hnlo, pli, poi, plo, poo, states, out_p, out_y);
        _Float16* t;
        t = hchi; hchi = hnhi; hnhi = t;
        t = hclo; hclo = hnlo; hnlo = t;
    }
    // halt(20): partials written by gemm(19) at parity 19&1 = 1
    finish_halt_kernel<<<dim3(B_N / 256), blk, 0, stream>>>(NSTEPS, pl1, po1,
                                                            b_out, b_lam, u, states,
                                                            out_p, out_y, out_pm, out_ym);
}

// Round 13
// 1205.216 us; speedup vs baseline: 1.2350x; 1.1287x over previous
//
#include <hip/hip_runtime.h>
#include <math.h>

// ParityPonderGRU — r3 configuration restored EXACTLY (step kernel + halt
// byte-identical to the 1282-us bench) with ONE change: gx GEMM moved to MFMA
// (fp32 VALU 98us -> ~13us). B=2048, E=512, H=1024, 20 ponder steps.
// ws layout: gx f32[B*3H] | Whi f16[3H*H] | Wlo f16[3H*H] |
//            hAhi f16[B*H] | hAlo | hBhi | hBlo | states f32[4*B]

#define B_N 2048
#define E_N 512
#define H_N 1024
#define G3  3072
#define NSTEPS 20
#define BK 32
#define NT (H_N / BK)     // 32 K-steps (step GEMM)
#define NT_E (E_N / BK)   // 16 K-steps (gx GEMM)

typedef __attribute__((ext_vector_type(8))) _Float16 f16x8;
typedef __attribute__((ext_vector_type(4))) _Float16 f16x4v;
typedef __attribute__((ext_vector_type(4))) float    f32x4;

#define GLDS(src, dst) \
  __builtin_amdgcn_global_load_lds( \
      (const __attribute__((address_space(1))) void*)(src), \
      (__attribute__((address_space(3))) void*)(dst), 16, 0, 0)

__device__ __forceinline__ float sigmoidf_(float x) { return 1.0f / (1.0f + expf(-x)); }

// ---------------- Fused step GEMM: gh = h @ W_hh^T (3-product split-fp16 MFMA)
// Block 128(B) x 64(H) x 3 gates; 4 waves 2x2; wave tile 64x32 per gate.
// LDS per buffer (halves): Ahi[0,4096) Alo[4096,8192) Bhi[8192,14336) Blo[14336,20480)
// = 40 KB/buffer, double-buffered = 80 KB. Unpadded [row][32] f16 rows (64 B),
// chunk c = 1 KB = 16 rows x 4 segs, lane-linear (global_load_lds dest order).
// BYTE-IDENTICAL to the kernel that benched 1282 us total (r3).
__global__ __launch_bounds__(256, 1)
void gemm_step_mfma(const _Float16* __restrict__ h_hi_in,  // [B,H]
                    const _Float16* __restrict__ h_lo_in,  // [B,H]
                    const _Float16* __restrict__ Whi,      // [3H,H]
                    const _Float16* __restrict__ Wlo,      // [3H,H]
                    const float* __restrict__ b_hh,        // [3H]
                    const float* __restrict__ gx,          // [B,3H]
                    _Float16* __restrict__ h_hi_out,
                    _Float16* __restrict__ h_lo_out)
{
  __shared__ _Float16 lds[2][20480];   // 81920 B

  const int tid  = threadIdx.x;
  const int lane = tid & 63;
  const int wv   = tid >> 6;
  const int wr   = wv >> 1;    // row half (0..1)
  const int wc   = wv & 1;     // col half (0..1)
  const int row0 = blockIdx.y * 128;   // over B
  const int col0 = blockIdx.x * 64;    // over H

  // --- per-wave staging chunks: 40 chunks of 1 KB; wave wv owns [wv*10, wv*10+10)
  const _Float16* srcp[10];
  int ldsoff[10];
  #pragma unroll
  for (int j = 0; j < 10; ++j) {
    const int c   = wv * 10 + j;
    const int seg = (lane & 3) * 8;        // k offset in elements
    const _Float16* s;
    if (c < 8) {                                  // A-hi rows 0..127
      const int row = c * 16 + (lane >> 2);
      s = h_hi_in + (size_t)(row0 + row) * H_N + seg;
    } else if (c < 16) {                          // A-lo
      const int row = (c - 8) * 16 + (lane >> 2);
      s = h_lo_in + (size_t)(row0 + row) * H_N + seg;
    } else if (c < 28) {                          // B-hi rows 0..191 (3 gates x 64)
      const int br   = (c - 16) * 16 + (lane >> 2);
      const int wrow = (br >> 6) * H_N + col0 + (br & 63);
      s = Whi + (size_t)wrow * H_N + seg;
    } else {                                      // B-lo
      const int br   = (c - 28) * 16 + (lane >> 2);
      const int wrow = (br >> 6) * H_N + col0 + (br & 63);
      s = Wlo + (size_t)wrow * H_N + seg;
    }
    srcp[j]   = s;
    ldsoff[j] = c * 512;                  // halves
  }

  f32x4 acc[3][4][2];
  #pragma unroll
  for (int g = 0; g < 3; ++g)
    #pragma unroll
    for (int mi = 0; mi < 4; ++mi)
      #pragma unroll
      for (int ni = 0; ni < 2; ++ni)
        acc[g][mi][ni] = (f32x4){0.f, 0.f, 0.f, 0.f};

  const int lrow = lane & 15;
  const int lk   = (lane >> 4) * 8;

  // prologue: stage tile 0 into buffer 0
  #pragma unroll
  for (int j = 0; j < 10; ++j) {
    GLDS(srcp[j], &lds[0][ldsoff[j]]);
    srcp[j] += BK;
  }
  __syncthreads();

  for (int t = 0; t < NT; ++t) {
    const int p = t & 1;
    if (t + 1 < NT) {
      #pragma unroll
      for (int j = 0; j < 10; ++j) {
        GLDS(srcp[j], &lds[p ^ 1][ldsoff[j]]);
        srcp[j] += BK;
      }
    }
    // LDS -> fragments
    f16x8 ah[4], al[4];
    #pragma unroll
    for (int mi = 0; mi < 4; ++mi) {
      const int r = wr * 64 + mi * 16 + lrow;
      ah[mi] = *(const f16x8*)&lds[p][r * 32 + lk];
      al[mi] = *(const f16x8*)&lds[p][4096 + r * 32 + lk];
    }
    f16x8 bh[3][2], bl[3][2];
    #pragma unroll
    for (int g = 0; g < 3; ++g)
      #pragma unroll
      for (int ni = 0; ni < 2; ++ni) {
        const int r = g * 64 + wc * 32 + ni * 16 + lrow;
        bh[g][ni] = *(const f16x8*)&lds[p][8192 + r * 32 + lk];
        bl[g][ni] = *(const f16x8*)&lds[p][14336 + r * 32 + lk];
      }
    #pragma unroll
    for (int g = 0; g < 3; ++g)
      #pragma unroll
      for (int mi = 0; mi < 4; ++mi)
        #pragma unroll
        for (int ni = 0; ni < 2; ++ni) {
          f32x4 c = acc[g][mi][ni];
          c = __builtin_amdgcn_mfma_f32_16x16x32_f16(ah[mi], bh[g][ni], c, 0, 0, 0);
          c = __builtin_amdgcn_mfma_f32_16x16x32_f16(ah[mi], bl[g][ni], c, 0, 0, 0);
          c = __builtin_amdgcn_mfma_f32_16x16x32_f16(al[mi], bh[g][ni], c, 0, 0, 0);
          acc[g][mi][ni] = c;
        }
    __syncthreads();
  }

  // Gate epilogue: D frag mapping col=lane&15, row=(lane>>4)*4+r  [m89]
  #pragma unroll
  for (int mi = 0; mi < 4; ++mi) {
    #pragma unroll
    for (int ni = 0; ni < 2; ++ni) {
      const int n = col0 + wc * 32 + ni * 16 + lrow;
      const float bhr = b_hh[n];
      const float bhz = b_hh[H_N + n];
      const float bhn = b_hh[2 * H_N + n];
      #pragma unroll
      for (int r = 0; r < 4; ++r) {
        const int m = row0 + wr * 64 + mi * 16 + (lane >> 4) * 4 + r;
        const float gr = acc[0][mi][ni][r] + bhr;
        const float gz = acc[1][mi][ni][r] + bhz;
        const float gn = acc[2][mi][ni][r] + bhn;
        const size_t gxb = (size_t)m * G3;
        const float rr = sigmoidf_(gx[gxb + n] + gr);
        const float zz = sigmoidf_(gx[gxb + H_N + n] + gz);
        const float nn = tanhf(gx[gxb + 2 * H_N + n] + rr * gn);
        const size_t hidx = (size_t)m * H_N + n;
        const float hold = (float)h_hi_in[hidx] + (float)h_lo_in[hidx];
        const float hf = (1.f - zz) * nn + zz * hold;
        const _Float16 hh = (_Float16)hf;
        h_hi_out[hidx] = hh;
        h_lo_out[hidx] = (_Float16)(hf - (float)hh);
      }
    }
  }
}

// ---------------- gx GEMM (MFMA): gx = x @ W_ih^T + b_ih  (proven r8+) ------
__global__ __launch_bounds__(256, 3)
void gemm_gx_mfma(const _Float16* __restrict__ xhi,    // [B,E]
                  const _Float16* __restrict__ xlo,
                  const _Float16* __restrict__ Wihhi,  // [3H,E]
                  const _Float16* __restrict__ Wihlo,
                  const float* __restrict__ b_ih,
                  float* __restrict__ gx)              // [B,3H]
{
  __shared__ _Float16 lds[2][12288];   // 49152 B

  const int tid  = threadIdx.x;
  const int lane = tid & 63;
  const int wv   = tid >> 6;
  const int wr   = wv >> 1;
  const int wc   = wv & 1;
  const int row0 = blockIdx.y * 128;   // over B
  const int col0 = blockIdx.x * 64;    // over 3H

  const _Float16* srcp[6];
  int ldsoff[6];
  #pragma unroll
  for (int j = 0; j < 6; ++j) {
    const int c     = wv * 6 + j;
    const int seg   = (lane & 3) * 8;
    const int row16 = lane >> 2;
    const _Float16* s;
    if (c < 8)       s = xhi   + (size_t)(row0 + c * 16 + row16) * E_N + seg;
    else if (c < 16) s = xlo   + (size_t)(row0 + (c - 8) * 16 + row16) * E_N + seg;
    else if (c < 20) s = Wihhi + (size_t)(col0 + (c - 16) * 16 + row16) * E_N + seg;
    else             s = Wihlo + (size_t)(col0 + (c - 20) * 16 + row16) * E_N + seg;
    srcp[j]   = s;
    ldsoff[j] = c * 512;
  }

  f32x4 acc[4][2];
  #pragma unroll
  for (int mi = 0; mi < 4; ++mi)
    #pragma unroll
    for (int ni = 0; ni < 2; ++ni) acc[mi][ni] = (f32x4){0.f, 0.f, 0.f, 0.f};

  const int lrow = lane & 15;
  const int lk   = (lane >> 4) * 8;
  const int q    = lane >> 4;

  #pragma unroll
  for (int j = 0; j < 6; ++j) { GLDS(srcp[j], &lds[0][ldsoff[j]]); srcp[j] += BK; }
  __syncthreads();

  for (int t = 0; t < NT_E; ++t) {
    const int p = t & 1;
    if (t + 1 < NT_E) {
      #pragma unroll
      for (int j = 0; j < 6; ++j) { GLDS(srcp[j], &lds[p ^ 1][ldsoff[j]]); srcp[j] += BK; }
    }
    f16x8 ah[4], al[4];
    #pragma unroll
    for (int mi = 0; mi < 4; ++mi) {
      const int r = wr * 64 + mi * 16 + lrow;
      ah[mi] = *(const f16x8*)&lds[p][r * 32 + lk];
      al[mi] = *(const f16x8*)&lds[p][4096 + r * 32 + lk];
    }
    f16x8 bh[2], bl[2];
    #pragma unroll
    for (int ni = 0; ni < 2; ++ni) {
      const int r = wc * 32 + ni * 16 + lrow;
      bh[ni] = *(const f16x8*)&lds[p][8192 + r * 32 + lk];
      bl[ni] = *(const f16x8*)&lds[p][10240 + r * 32 + lk];
    }
    #pragma unroll
    for (int mi = 0; mi < 4; ++mi)
      #pragma unroll
      for (int ni = 0; ni < 2; ++ni) {
        f32x4 c = acc[mi][ni];
        c = __builtin_amdgcn_mfma_f32_16x16x32_f16(ah[mi], bh[ni], c, 0, 0, 0);
        c = __builtin_amdgcn_mfma_f32_16x16x32_f16(ah[mi], bl[ni], c, 0, 0, 0);
        c = __builtin_amdgcn_mfma_f32_16x16x32_f16(al[mi], bh[ni], c, 0, 0, 0);
        acc[mi][ni] = c;
      }
    __syncthreads();
  }

  #pragma unroll
  for (int mi = 0; mi < 4; ++mi) {
    #pragma unroll
    for (int ni = 0; ni < 2; ++ni) {
      const int n = col0 + wc * 32 + ni * 16 + lrow;
      const float bi = b_ih[n];
      #pragma unroll
      for (int r = 0; r < 4; ++r) {
        const int m = row0 + wr * 64 + mi * 16 + q * 4 + r;
        gx[(size_t)m * G3 + n] = acc[mi][ni][r] + bi;
      }
    }
  }
}

// ---------------- one-time: split fp32 -> fp16 hi/lo -----------------------
__global__ __launch_bounds__(256)
void split_f32_kernel(const float* __restrict__ src,
                      _Float16* __restrict__ hi, _Float16* __restrict__ lo)
{
  const size_t base = ((size_t)blockIdx.x * 256 + threadIdx.x) * 4;
  const float4 w = *(const float4*)&src[base];
  float s[4] = {w.x, w.y, w.z, w.w};
  f16x4v h4, l4;
  #pragma unroll
  for (int e = 0; e < 4; ++e) {
    const _Float16 h = (_Float16)s[e];
    h4[e] = h;
    l4[e] = (_Float16)(s[e] - (float)h);
  }
  *(f16x4v*)&hi[base] = h4;
  *(f16x4v*)&lo[base] = l4;
}

// ---------------- h0 = gru_cell(x, 0): gh = b_hh; init states --------------
__global__ __launch_bounds__(256)
void init_h0_kernel(const float* __restrict__ gx, const float* __restrict__ b_hh,
                    _Float16* __restrict__ h_hi, _Float16* __restrict__ h_lo,
                    float* __restrict__ states)
{
    const int idx = blockIdx.x * 256 + threadIdx.x;
    const int r = idx >> 10;
    const int c = idx & (H_N - 1);
    const float rr = sigmoidf_(gx[(size_t)r * G3 + c] + b_hh[c]);
    const float zz = sigmoidf_(gx[(size_t)r * G3 + H_N + c] + b_hh[H_N + c]);
    const float nn = tanhf(gx[(size_t)r * G3 + 2 * H_N + c] + rr * b_hh[2 * H_N + c]);
    const float hf = (1.0f - zz) * nn;
    const _Float16 hh = (_Float16)hf;
    h_hi[idx] = hh;
    h_lo[idx] = (_Float16)(hf - (float)hh);
    if (idx < B_N) {
        states[idx]           = 1.0f;
        states[B_N + idx]     = 0.0f;
        states[2 * B_N + idx] = 0.0f;
        states[3 * B_N + idx] = 0.0f;
    }
}

// ---------------- Per-step halting (standalone, r3-identical) ---------------
__global__ __launch_bounds__(256)
void halt_kernel(const int n,
                 const _Float16* __restrict__ h_hi, const _Float16* __restrict__ h_lo,
                 const float* __restrict__ w_out, const float* __restrict__ b_out,
                 const float* __restrict__ w_lam, const float* __restrict__ b_lam,
                 const float* __restrict__ u,
                 float* __restrict__ states,
                 float* __restrict__ out_p, float* __restrict__ out_y,
                 float* __restrict__ out_pm, float* __restrict__ out_ym)
{
    const int row = blockIdx.x;
    const int tid = threadIdx.x;
    const size_t base = (size_t)row * H_N + (tid << 2);
    const f16x4v hh4 = *(const f16x4v*)&h_hi[base];
    const f16x4v hl4 = *(const f16x4v*)&h_lo[base];
    const float4 wl = *(const float4*)&w_lam[tid << 2];
    const float4 wo = *(const float4*)&w_out[tid << 2];
    float hv[4];
    #pragma unroll
    for (int e = 0; e < 4; ++e) hv[e] = (float)hh4[e] + (float)hl4[e];
    float s_lam = hv[0] * wl.x + hv[1] * wl.y + hv[2] * wl.z + hv[3] * wl.w;
    float s_out = hv[0] * wo.x + hv[1] * wo.y + hv[2] * wo.z + hv[3] * wo.w;
    #pragma unroll
    for (int off = 32; off > 0; off >>= 1) {
        s_lam += __shfl_down(s_lam, off);
        s_out += __shfl_down(s_out, off);
    }
    __shared__ float redl[4], redo[4];
    const int wid = tid >> 6;
    if ((tid & 63) == 0) { redl[wid] = s_lam; redo[wid] = s_out; }
    __syncthreads();
    if (tid == 0) {
        const float dlam = redl[0] + redl[1] + redl[2] + redl[3];
        const float dout = redo[0] + redo[1] + redo[2] + redo[3];
        const float lam = (n == NSTEPS) ? 1.0f : sigmoidf_(dlam + b_lam[0]);
        const float y_n = dout + b_out[0];
        float un = states[row];
        float ha = states[B_N + row];
        float pm = states[2 * B_N + row];
        float ym = states[3 * B_N + row];
        const float p_n = un * lam;
        un = un * (1.0f - lam);
        const float halt = (u[(size_t)(n - 1) * B_N + row] < lam ? 1.0f : 0.0f) * (1.0f - ha);
        pm = pm * (1.0f - halt) + p_n * halt;
        ym = ym * (1.0f - halt) + y_n * halt;
        ha += halt;
        states[row] = un;
        states[B_N + row] = ha;
        states[2 * B_N + row] = pm;
        states[3 * B_N + row] = ym;
        out_p[(size_t)(n - 1) * B_N + row] = p_n;
        out_y[(size_t)(n - 1) * B_N + row] = y_n;
        if (n == NSTEPS) { out_pm[row] = pm; out_ym[row] = ym; }
    }
}

extern "C" void kernel_launch(void* const* d_in, const int* in_sizes, int n_in,
                              void* d_out, int out_size, void* d_ws, size_t ws_size,
                              hipStream_t stream) {
    const float* x     = (const float*)d_in[0];
    const float* W_ih  = (const float*)d_in[1];
    const float* W_hh  = (const float*)d_in[2];
    const float* b_ih  = (const float*)d_in[3];
    const float* b_hh  = (const float*)d_in[4];
    const float* w_out = (const float*)d_in[5];
    const float* b_out = (const float*)d_in[6];
    const float* w_lam = (const float*)d_in[7];
    const float* b_lam = (const float*)d_in[8];
    const float* u     = (const float*)d_in[9];

    float* out_p  = (float*)d_out;
    float* out_y  = out_p + (size_t)NSTEPS * B_N;
    float* out_pm = out_y + (size_t)NSTEPS * B_N;
    float* out_ym = out_pm + B_N;

    float* ws = (float*)d_ws;
    float*     gx   = ws;                                    // B*3H f32
    _Float16*  Whi  = (_Float16*)(gx + (size_t)B_N * G3);    // 3H*H f16
    _Float16*  Wlo  = Whi + (size_t)G3 * H_N;
    _Float16*  hAhi = Wlo + (size_t)G3 * H_N;                // B*H f16
    _Float16*  hAlo = hAhi + (size_t)B_N * H_N;
    _Float16*  hBhi = hAlo + (size_t)B_N * H_N;
    _Float16*  hBlo = hBhi + (size_t)B_N * H_N;
    float*     states = (float*)(hBlo + (size_t)B_N * H_N);  // 4*B f32

    const dim3 blk(256);
    // one-time splits (W_ih -> hA*, x -> hB*: buffers not yet live)
    split_f32_kernel<<<dim3((size_t)G3 * H_N / 1024), blk, 0, stream>>>(W_hh, Whi, Wlo);
    split_f32_kernel<<<dim3((size_t)G3 * E_N / 1024), blk, 0, stream>>>(W_ih, hAhi, hAlo);
    split_f32_kernel<<<dim3((size_t)B_N * E_N / 1024), blk, 0, stream>>>(x, hBhi, hBlo);
    gemm_gx_mfma<<<dim3(G3 / 64, B_N / 128), blk, 0, stream>>>(hBhi, hBlo, hAhi, hAlo, b_ih, gx);
    init_h0_kernel<<<dim3(B_N * H_N / 256), blk, 0, stream>>>(gx, b_hh, hAhi, hAlo, states);

    _Float16 *hchi = hAhi, *hclo = hAlo, *hnhi = hBhi, *hnlo = hBlo;
    for (int n = 1; n <= NSTEPS; ++n) {
        halt_kernel<<<dim3(B_N), blk, 0, stream>>>(n, hchi, hclo, w_out, b_out, w_lam, b_lam, u,
                                                   states, out_p, out_y, out_pm, out_ym);
        if (n < NSTEPS) {
            gemm_step_mfma<<<dim3(H_N / 64, B_N / 128), blk, 0, stream>>>(
                hchi, hclo, Whi, Wlo, b_hh, gx, hnhi, hnlo);
            _Float16* t;
            t = hchi; hchi = hnhi; hnhi = t;
            t = hclo; hclo = hnlo; hnlo = t;
        }
    }
}